// Round 2
// baseline (1849.484 us; speedup 1.0000x reference)
//
#include <hip/hip_runtime.h>

// RNNModel: h_{t+1} = hardtanh(x_t @ W_in^T + h_t @ W_h^T), out = h_T @ W_out^T
// B=1024 T=2048 D=13 H=128 O=2, all fp32.
//
// Strategy (round 1, fp32 vector-ALU baseline):
//  - 512 persistent blocks x 256 threads, BB=2 batches per block, loop over T inside.
//  - Thread (i = tid&127, half = tid>>7) owns W_h[i][half*64 .. half*64+63] in VGPRs.
//  - h[2][128] in LDS; reads are wave-uniform broadcasts (no bank conflicts).
//  - half==1 threads additionally fuse the W_in projection (x staged in LDS,
//    double-buffered one step ahead).
//  - 2 __syncthreads per step (partial-combine, h-update).

#define RNN_B 1024
#define RNN_T 2048
#define RNN_D 13
#define RNN_H 128
#define RNN_O 2

#define BB 2              // batches per block
#define NBLK (RNN_B / BB) // 512
#define NTHR 256

__global__ __launch_bounds__(NTHR, 2) void rnn_persistent_kernel(
    const float* __restrict__ xs,     // [B, T, D]
    const float* __restrict__ W_in,   // [H, D]
    const float* __restrict__ W_h,    // [H, H]
    const float* __restrict__ W_out,  // [O, H]
    float* __restrict__ out)          // [B, O]
{
    __shared__ __align__(16) float h[BB][RNN_H];     // hidden state
    __shared__ __align__(16) float part[BB][RNN_H];  // half-1 partials (+ pre)
    __shared__ __align__(16) float xbuf[2][BB][16];  // staged x_t (13 used)

    const int tid  = threadIdx.x;
    const int i    = tid & 127;
    const int half = tid >> 7;      // 0 or 1
    const int b0   = blockIdx.x * BB;
    const int jb   = half * 64;

    // --- pin W_h row-half in registers (64 floats) ---
    float w[64];
    {
        const float* wrow = W_h + i * RNN_H + jb;
        #pragma unroll
        for (int k = 0; k < 16; ++k) {
            float4 v = *reinterpret_cast<const float4*>(wrow + 4 * k);
            w[4*k+0] = v.x; w[4*k+1] = v.y; w[4*k+2] = v.z; w[4*k+3] = v.w;
        }
    }
    // --- half-1 threads pin W_in row (13 floats) ---
    float wi[RNN_D];
    if (half) {
        #pragma unroll
        for (int d = 0; d < RNN_D; ++d) wi[d] = W_in[i * RNN_D + d];
    }

    // --- init h = 0, stage x_0 ---
    h[half][i] = 0.0f;  // tid 0..255 covers BB*H = 256 entries exactly (half==b here)
    int sb = -1, sd = 0;
    if (tid >= NTHR - BB * 16) {
        int r = tid - (NTHR - BB * 16);
        sb = r >> 4; sd = r & 15;
        if (sd >= RNN_D) sb = -1;
    }
    if (sb >= 0) xbuf[0][sb][sd] = xs[(size_t)(b0 + sb) * RNN_T * RNN_D + sd];
    __syncthreads();

    // --- recurrence over T ---
    for (int t = 0; t < RNN_T; ++t) {
        const int cur = t & 1, nxt = cur ^ 1;

        // stage x_{t+1} (consumed next step; double-buffered)
        if (sb >= 0 && (t + 1) < RNN_T)
            xbuf[nxt][sb][sd] =
                xs[(size_t)(b0 + sb) * RNN_T * RNN_D + (size_t)(t + 1) * RNN_D + sd];

        // partial dot over this thread's 64-wide j slice (broadcast LDS reads)
        float a00 = 0.f, a01 = 0.f, a10 = 0.f, a11 = 0.f;
        #pragma unroll
        for (int k = 0; k < 32; k += 4) {
            float4 ha = *reinterpret_cast<const float4*>(&h[0][jb + k]);
            float4 hb = *reinterpret_cast<const float4*>(&h[1][jb + k]);
            float4 hc = *reinterpret_cast<const float4*>(&h[0][jb + 32 + k]);
            float4 hd = *reinterpret_cast<const float4*>(&h[1][jb + 32 + k]);
            a00 = fmaf(w[k+0], ha.x, a00); a00 = fmaf(w[k+1], ha.y, a00);
            a00 = fmaf(w[k+2], ha.z, a00); a00 = fmaf(w[k+3], ha.w, a00);
            a10 = fmaf(w[k+0], hb.x, a10); a10 = fmaf(w[k+1], hb.y, a10);
            a10 = fmaf(w[k+2], hb.z, a10); a10 = fmaf(w[k+3], hb.w, a10);
            a01 = fmaf(w[32+k+0], hc.x, a01); a01 = fmaf(w[32+k+1], hc.y, a01);
            a01 = fmaf(w[32+k+2], hc.z, a01); a01 = fmaf(w[32+k+3], hc.w, a01);
            a11 = fmaf(w[32+k+0], hd.x, a11); a11 = fmaf(w[32+k+1], hd.y, a11);
            a11 = fmaf(w[32+k+2], hd.z, a11); a11 = fmaf(w[32+k+3], hd.w, a11);
        }

        if (half) {
            // fuse input projection for this step
            float p0 = 0.f, p1 = 0.f;
            #pragma unroll
            for (int d = 0; d < RNN_D; ++d) {
                p0 = fmaf(wi[d], xbuf[cur][0][d], p0);
                p1 = fmaf(wi[d], xbuf[cur][1][d], p1);
            }
            part[0][i] = a00 + a01 + p0;
            part[1][i] = a10 + a11 + p1;
        }
        __syncthreads();  // partials visible; all h reads complete

        if (!half) {
            float v0 = a00 + a01 + part[0][i];
            float v1 = a10 + a11 + part[1][i];
            v0 = fminf(fmaxf(v0, -1.0f), 1.0f);
            v1 = fminf(fmaxf(v1, -1.0f), 1.0f);
            h[0][i] = v0;
            h[1][i] = v1;
        }
        __syncthreads();  // updated h visible
    }

    // --- epilogue: out[b][o] = sum_i W_out[o][i] * h[b][i] ---
    if (tid < BB * RNN_O) {
        const int b = tid >> 1, o = tid & 1;
        float s = 0.f;
        #pragma unroll 4
        for (int k = 0; k < RNN_H; k += 4) {
            float4 wv = *reinterpret_cast<const float4*>(&W_out[o * RNN_H + k]);
            s = fmaf(wv.x, h[b][k+0], s);
            s = fmaf(wv.y, h[b][k+1], s);
            s = fmaf(wv.z, h[b][k+2], s);
            s = fmaf(wv.w, h[b][k+3], s);
        }
        out[(size_t)(b0 + b) * RNN_O + o] = s;
    }
}

extern "C" void kernel_launch(void* const* d_in, const int* in_sizes, int n_in,
                              void* d_out, int out_size, void* d_ws, size_t ws_size,
                              hipStream_t stream) {
    const float* xs    = (const float*)d_in[0];
    const float* W_in  = (const float*)d_in[1];
    const float* W_h   = (const float*)d_in[2];
    const float* W_out = (const float*)d_in[3];
    float* out = (float*)d_out;

    rnn_persistent_kernel<<<NBLK, NTHR, 0, stream>>>(xs, W_in, W_h, W_out, out);
}

// Round 3
// 1691.397 us; speedup vs baseline: 1.0935x; 1.0935x over previous
//
#include <hip/hip_runtime.h>

// RNNModel: h_{t+1} = hardtanh(x_t @ W_in^T + h_t @ W_h^T), out = h_T @ W_out^T
// B=1024 T=2048 D=13 H=128 O=2, all fp32.
//
// Round 3: row-per-thread fp32 design.
//  - 1024 blocks x 128 threads, ONE batch per block, thread i owns W_h row i
//    (128 floats pinned in VGPRs via "+v" keep-alive asm each iteration —
//    round 2 showed VGPR_Count=60, i.e. the compiler reloaded W_h from L2
//    every step instead of pinning).
//  - h double-buffered in LDS; all h reads are wave-uniform b128 broadcasts;
//    ONE __syncthreads per step (read->fma dependence orders reads before the
//    barrier, so write-after-read on the other buffer is safe).
//  - x_t address is wave-uniform -> compiler emits s_load, x values live in
//    SGPRs (v_fmac with SGPR src0), SMEM pipe is otherwise idle. Prefetched
//    one step ahead.
//  - Epilogue: W_out projection via wave shuffle-reduce.

#define RNN_B 1024
#define RNN_T 2048
#define RNN_D 13
#define RNN_H 128
#define RNN_O 2
#define NTHR  128

__global__ __launch_bounds__(NTHR, 2) void rnn_row_kernel(
    const float* __restrict__ xs,     // [B, T, D]
    const float* __restrict__ W_in,   // [H, D]
    const float* __restrict__ W_h,    // [H, H]
    const float* __restrict__ W_out,  // [O, H]
    float* __restrict__ out)          // [B, O]
{
    __shared__ __align__(16) float h[2][RNN_H];
    __shared__ float red[RNN_O * (NTHR / 64)];

    const int i = threadIdx.x;   // hidden row this thread owns
    const int b = blockIdx.x;    // batch this block owns

    // --- pin W_h row i (128 floats) and W_in row i (13 floats) ---
    float w[RNN_H];
    {
        const float* wrow = W_h + i * RNN_H;
        #pragma unroll
        for (int k = 0; k < RNN_H / 4; ++k) {
            float4 v = *reinterpret_cast<const float4*>(wrow + 4 * k);
            w[4*k+0] = v.x; w[4*k+1] = v.y; w[4*k+2] = v.z; w[4*k+3] = v.w;
        }
    }
    float wi[RNN_D];
    #pragma unroll
    for (int d = 0; d < RNN_D; ++d) wi[d] = W_in[i * RNN_D + d];

    // --- init h0 = 0; prefetch x_0 (uniform -> SGPRs) ---
    h[0][i] = 0.0f;
    const float* xb = xs + (size_t)b * RNN_T * RNN_D;
    float xc[RNN_D];
    #pragma unroll
    for (int d = 0; d < RNN_D; ++d) xc[d] = xb[d];
    __syncthreads();

    float hlast = 0.0f;

    for (int t = 0; t < RNN_T; ++t) {
        const int cur = t & 1;

        // keep the weight rows pinned in VGPRs across the whole loop:
        // "+v" marks each value as modified-in-register, blocking
        // rematerialization/reload from global.
        #pragma unroll
        for (int k = 0; k < RNN_H; ++k) asm volatile("" : "+v"(w[k]));
        #pragma unroll
        for (int d = 0; d < RNN_D; ++d) asm volatile("" : "+v"(wi[d]));

        // prefetch x_{t+1} (uniform s_loads; latency hidden under the FMAs)
        float xn[RNN_D];
        if (t + 1 < RNN_T) {
            const float* xp = xb + (size_t)(t + 1) * RNN_D;
            #pragma unroll
            for (int d = 0; d < RNN_D; ++d) xn[d] = xp[d];
        } else {
            #pragma unroll
            for (int d = 0; d < RNN_D; ++d) xn[d] = 0.0f;
        }

        // input projection for this step (SGPR x, VGPR wi)
        float acc = 0.0f;
        #pragma unroll
        for (int d = 0; d < RNN_D; ++d) acc = fmaf(wi[d], xc[d], acc);

        // recurrent dot: 32 broadcast b128 LDS reads + 128 FMAs
        const float* hc = h[cur];
        #pragma unroll
        for (int k = 0; k < RNN_H / 4; ++k) {
            float4 hv = *reinterpret_cast<const float4*>(hc + 4 * k);
            acc = fmaf(w[4*k+0], hv.x, acc);
            acc = fmaf(w[4*k+1], hv.y, acc);
            acc = fmaf(w[4*k+2], hv.z, acc);
            acc = fmaf(w[4*k+3], hv.w, acc);
        }

        acc = fminf(fmaxf(acc, -1.0f), 1.0f);
        h[cur ^ 1][i] = acc;
        hlast = acc;

        #pragma unroll
        for (int d = 0; d < RNN_D; ++d) xc[d] = xn[d];

        __syncthreads();  // h[cur^1] complete before next step reads it
    }

    // --- epilogue: out[b][o] = sum_i W_out[o][i] * h_T[i] ---
    float c0 = W_out[0 * RNN_H + i] * hlast;
    float c1 = W_out[1 * RNN_H + i] * hlast;
    #pragma unroll
    for (int d = 32; d >= 1; d >>= 1) {
        c0 += __shfl_down(c0, d, 64);
        c1 += __shfl_down(c1, d, 64);
    }
    const int wv = i >> 6;               // wave id (0 or 1)
    if ((i & 63) == 0) {
        red[wv * RNN_O + 0] = c0;
        red[wv * RNN_O + 1] = c1;
    }
    __syncthreads();
    if (i < RNN_O) {
        out[(size_t)b * RNN_O + i] = red[0 * RNN_O + i] + red[1 * RNN_O + i];
    }
}

extern "C" void kernel_launch(void* const* d_in, const int* in_sizes, int n_in,
                              void* d_out, int out_size, void* d_ws, size_t ws_size,
                              hipStream_t stream) {
    const float* xs    = (const float*)d_in[0];
    const float* W_in  = (const float*)d_in[1];
    const float* W_h   = (const float*)d_in[2];
    const float* W_out = (const float*)d_in[3];
    float* out = (float*)d_out;

    rnn_row_kernel<<<RNN_B, NTHR, 0, stream>>>(xs, W_in, W_h, W_out, out);
}

// Round 4
// 1254.690 us; speedup vs baseline: 1.4741x; 1.3481x over previous
//
#include <hip/hip_runtime.h>
#include <stdint.h>

// RNNModel: h_{t+1} = hardtanh(x_t @ W_in^T + h_t @ W_h^T), out = h_T @ W_out^T
// B=1024 T=2048 D=13 H=128 O=2, fp32 in/out.
//
// Round 4: MFMA formulation (16x16x32 bf16, hi/lo split for ~fp32 accuracy).
//  - Augmented GEMM: D[i][n] = sum_k Waug[i][k] * Baug[k][n], K = 160
//    (k<128: h; k=128..140: x_t; rest zero-pad). 5 k-tiles of 32.
//  - hi/lo split: W = Whi+Wlo, h = hhi+hlo (bf16 each);
//    D = Whi*hhi + Whi*hlo + Wlo*hhi (3 MFMAs/k-tile; lo*lo dropped ~2^-18).
//  - Per block: NB=16 batches, 4 waves x 2 m-tiles (16 rows each). 64 blocks.
//  - h in LDS as bf16 hi/lo, layout hbf[buf][n][k] (k contiguous, padded row).
//    Write from verified D-layout: lane l holds rows 4*(l>>4)+r, col l&15
//    -> 4 consecutive k -> one b64 write per (mt, hi/lo).
//    Read as B-fragments: regs[0:1] <-> k=4g+j, regs[2:3] <-> k=16+4g+j
//    (g=lane>>4) -> two b64 reads per k-tile. (Layout inferred from the
//    ds_read_b64_tr_b16 hardware mapping, m156/m162.)
//  - One __syncthreads per step (double-buffered h).

#define RNN_B 1024
#define RNN_T 2048
#define RNN_D 13
#define RNN_H 128
#define RNN_O 2

#define NB 16                 // batches per block
#define NWAVE 4
#define NTHR (NWAVE * 64)
#define MTW 2                 // m-tiles per wave
#define NKT 5                 // k-tiles (4 for h, 1 for x)
#define HPAD 136              // padded per-batch k stride (shorts)

using f32x4 = __attribute__((ext_vector_type(4))) float;
using v8s   = __attribute__((ext_vector_type(8))) short;

__device__ __forceinline__ short f2bf(float f) {
    union { float f; uint32_t u; } c; c.f = f;
    uint32_t u = c.u + 0x7fffu + ((c.u >> 16) & 1u);   // RNE
    return (short)(u >> 16);
}
__device__ __forceinline__ float bf2f(short s) {
    union { uint32_t u; float f; } c; c.u = ((uint32_t)(uint16_t)s) << 16;
    return c.f;
}

__global__ __launch_bounds__(NTHR, 1) void rnn_mfma_kernel(
    const float* __restrict__ xs,     // [B, T, D]
    const float* __restrict__ W_in,   // [H, D]
    const float* __restrict__ W_h,    // [H, H]
    const float* __restrict__ W_out,  // [O, H]
    float* __restrict__ out)          // [B, O]
{
    __shared__ short hbf_hi[2][NB][HPAD];
    __shared__ short hbf_lo[2][NB][HPAD];

    const int tid  = threadIdx.x;
    const int lane = tid & 63;
    const int wid  = tid >> 6;       // wave 0..3
    const int n    = lane & 15;      // B-col / D-col (batch within tile); also A-row m
    const int g    = lane >> 4;      // k-group 0..3
    const int b0   = blockIdx.x * NB;

    // ---- A fragments: W rows for this wave's 2 m-tiles, bf16 hi/lo ----
    v8s wa_hi[MTW][NKT], wa_lo[MTW][NKT];
    #pragma unroll
    for (int mi = 0; mi < MTW; ++mi) {
        const int row = 16 * (wid * MTW + mi) + n;   // hidden row (A-row m = lane&15)
        #pragma unroll
        for (int kt = 0; kt < NKT; ++kt) {
            v8s h8, l8;
            #pragma unroll
            for (int j = 0; j < 4; ++j) {
                float w1, w2;
                if (kt < 4) {
                    w1 = W_h[row * RNN_H + 32 * kt + 4 * g + j];
                    w2 = W_h[row * RNN_H + 32 * kt + 16 + 4 * g + j];
                } else {
                    const int kx = 4 * g + j;
                    w1 = (kx < RNN_D) ? W_in[row * RNN_D + kx] : 0.0f;
                    w2 = 0.0f;
                }
                const short h1 = f2bf(w1);
                const short l1 = f2bf(w1 - bf2f(h1));
                const short h2 = f2bf(w2);
                const short l2 = f2bf(w2 - bf2f(h2));
                h8[j] = h1; h8[4 + j] = h2;
                l8[j] = l1; l8[4 + j] = l2;
            }
            wa_hi[mi][kt] = h8;
            wa_lo[mi][kt] = l8;
        }
    }

    // ---- zero-init h buffer 0 (h0 = 0) ----
    {
        short* z0 = &hbf_hi[0][0][0];
        short* z1 = &hbf_lo[0][0][0];
        for (int idx = tid; idx < NB * HPAD; idx += NTHR) { z0[idx] = 0; z1[idx] = 0; }
    }

    // ---- preload x_0 (lane (g,n): x[b0+n][0][4g..4g+3], clamped in-bounds) ----
    float xv[4];
    {
        const float* xr = xs + ((size_t)(b0 + n) * RNN_T + 0) * RNN_D;
        #pragma unroll
        for (int j = 0; j < 4; ++j) { const int d = 4 * g + j; xv[j] = xr[d > 12 ? 12 : d]; }
    }
    __syncthreads();

    // ---- recurrence ----
    for (int t = 0; t < RNN_T; ++t) {
        const int cur = t & 1, nxt = cur ^ 1;

        // x B-fragment for this step (upper k-half is zero-pad)
        v8s xb_hi, xb_lo;
        #pragma unroll
        for (int j = 0; j < 4; ++j) {
            const int d = 4 * g + j;
            const float v = (d < RNN_D) ? xv[j] : 0.0f;
            const short h1 = f2bf(v);
            const short l1 = f2bf(v - bf2f(h1));
            xb_hi[j] = h1; xb_hi[4 + j] = 0;
            xb_lo[j] = l1; xb_lo[4 + j] = 0;
        }

        // prefetch x_{t+1} (latency hidden under MFMAs)
        if (t + 1 < RNN_T) {
            const float* xr = xs + ((size_t)(b0 + n) * RNN_T + (t + 1)) * RNN_D;
            #pragma unroll
            for (int j = 0; j < 4; ++j) { const int d = 4 * g + j; xv[j] = xr[d > 12 ? 12 : d]; }
        }

        // B-fragments of h (hi/lo) from LDS
        v8s bh[4], bl[4];
        #pragma unroll
        for (int kt = 0; kt < 4; ++kt) {
            const short* p = &hbf_hi[cur][n][32 * kt + 4 * g];
            const int2 r1 = *(const int2*)p;
            const int2 r2 = *(const int2*)(p + 16);
            union { int4 i; v8s s; } u; u.i = make_int4(r1.x, r1.y, r2.x, r2.y);
            bh[kt] = u.s;
            const short* q = &hbf_lo[cur][n][32 * kt + 4 * g];
            const int2 s1 = *(const int2*)q;
            const int2 s2 = *(const int2*)(q + 16);
            union { int4 i; v8s s; } v; v.i = make_int4(s1.x, s1.y, s2.x, s2.y);
            bl[kt] = v.s;
        }

        // MFMA + epilogue per m-tile
        #pragma unroll
        for (int mi = 0; mi < MTW; ++mi) {
            f32x4 a1 = {0.f, 0.f, 0.f, 0.f};
            f32x4 a2 = {0.f, 0.f, 0.f, 0.f};
            f32x4 a3 = {0.f, 0.f, 0.f, 0.f};
            #pragma unroll
            for (int kt = 0; kt < 4; ++kt) {
                a1 = __builtin_amdgcn_mfma_f32_16x16x32_bf16(wa_hi[mi][kt], bh[kt], a1, 0, 0, 0);
                a2 = __builtin_amdgcn_mfma_f32_16x16x32_bf16(wa_hi[mi][kt], bl[kt], a2, 0, 0, 0);
                a3 = __builtin_amdgcn_mfma_f32_16x16x32_bf16(wa_lo[mi][kt], bh[kt], a3, 0, 0, 0);
            }
            a1 = __builtin_amdgcn_mfma_f32_16x16x32_bf16(wa_hi[mi][4], xb_hi, a1, 0, 0, 0);
            a2 = __builtin_amdgcn_mfma_f32_16x16x32_bf16(wa_hi[mi][4], xb_lo, a2, 0, 0, 0);
            a3 = __builtin_amdgcn_mfma_f32_16x16x32_bf16(wa_lo[mi][4], xb_hi, a3, 0, 0, 0);

            // D rows: 4*(lane>>4)+r (verified layout), col n. Sum, clip, split.
            short hs[4], ls[4];
            #pragma unroll
            for (int r = 0; r < 4; ++r) {
                float vv = a1[r] + a2[r] + a3[r];
                vv = fminf(fmaxf(vv, -1.0f), 1.0f);
                const short hh = f2bf(vv);
                hs[r] = hh;
                ls[r] = f2bf(vv - bf2f(hh));
            }
            const int krow = 16 * (wid * MTW + mi) + 4 * g;   // 4 consecutive k
            int2 ph, pl;
            ph.x = (int)(((uint32_t)(uint16_t)hs[1] << 16) | (uint16_t)hs[0]);
            ph.y = (int)(((uint32_t)(uint16_t)hs[3] << 16) | (uint16_t)hs[2]);
            pl.x = (int)(((uint32_t)(uint16_t)ls[1] << 16) | (uint16_t)ls[0]);
            pl.y = (int)(((uint32_t)(uint16_t)ls[3] << 16) | (uint16_t)ls[2]);
            *(int2*)&hbf_hi[nxt][n][krow] = ph;
            *(int2*)&hbf_lo[nxt][n][krow] = pl;
        }
        __syncthreads();
    }

    // ---- epilogue: out[b][o] = sum_i W_out[o][i] * h_T[i]  (final h in buf 0) ----
    if (wid == 0 && lane < NB * RNN_O) {
        const int nn = lane & 15;
        const int o  = lane >> 4;
        float acc = 0.0f;
        for (int i = 0; i < RNN_H; ++i) {
            const float hv = bf2f(hbf_hi[0][nn][i]) + bf2f(hbf_lo[0][nn][i]);
            acc = fmaf(W_out[o * RNN_H + i], hv, acc);
        }
        out[(size_t)(b0 + nn) * RNN_O + o] = acc;
    }
}

extern "C" void kernel_launch(void* const* d_in, const int* in_sizes, int n_in,
                              void* d_out, int out_size, void* d_ws, size_t ws_size,
                              hipStream_t stream) {
    const float* xs    = (const float*)d_in[0];
    const float* W_in  = (const float*)d_in[1];
    const float* W_h   = (const float*)d_in[2];
    const float* W_out = (const float*)d_in[3];
    float* out = (float*)d_out;

    rnn_mfma_kernel<<<RNN_B / NB, NTHR, 0, stream>>>(xs, W_in, W_h, W_out, out);
}